// Round 7
// baseline (363.592 us; speedup 1.0000x reference)
//
#include <hip/hip_runtime.h>

#define NUSER 100000
#define NITEM 50000
#define NEDGE 640000
#define NLINK 200000
#define GI 49    // ceil(NITEM/1024)
#define GU 98    // ceil(NUSER/1024)
#define NBU1 782 // ceil(NUSER/128)
#define NBI1 391 // ceil(NITEM/128)
#define NBG1 (NBU1 + NBI1)
#define FCHUNK 4096
#define FNCH 157 // ceil(NEDGE/4096)
// F0 = F1 = 128, F2 = 64

typedef unsigned int  uint;
typedef unsigned short ushort_t;
typedef __attribute__((ext_vector_type(8))) short bf16x8;
typedef __attribute__((ext_vector_type(4))) float f32x4;
typedef __attribute__((ext_vector_type(4))) uint  u32x4;

__device__ __forceinline__ ushort_t f2bf(float f) {           // RNE f32 -> bf16
    uint u = __float_as_uint(f);
    u += 0x7FFFu + ((u >> 16) & 1u);
    return (ushort_t)(u >> 16);
}
__device__ __forceinline__ float bf2f(ushort_t h) { return __uint_as_float(((uint)h) << 16); }
__device__ __forceinline__ float lo16f(uint u) { return __uint_as_float(u << 16); }
__device__ __forceinline__ float hi16f(uint u) { return __uint_as_float(u & 0xFFFF0000u); }

// ---------------------------------------------------------------------------
// Fused [degree count | weight pack] (unchanged from round 6).
// ---------------------------------------------------------------------------
__global__ __launch_bounds__(256) void countw_kernel(
    const int* __restrict__ src, const int* __restrict__ dst,
    int* __restrict__ cnt_u, int* __restrict__ cnt_i,
    const float* __restrict__ Wl0, const float* __restrict__ Wr0,
    const float* __restrict__ Wl1, const float* __restrict__ Wr1,
    const float* __restrict__ Wl2, const float* __restrict__ Wr2,
    const float* __restrict__ Wl3, const float* __restrict__ Wr3,
    ushort_t* __restrict__ Bh0, ushort_t* __restrict__ Bl0,
    ushort_t* __restrict__ Bh1, ushort_t* __restrict__ Bl1,
    ushort_t* __restrict__ Bh2, ushort_t* __restrict__ Bl2,
    ushort_t* __restrict__ Bh3, ushort_t* __restrict__ Bl3)
{
    if (blockIdx.x < 2500) {
        int e = blockIdx.x * 256 + threadIdx.x;
        if (e >= NEDGE) return;
        atomicAdd(&cnt_u[src[e]], 1);
        atomicAdd(&cnt_i[dst[e]], 1);
        return;
    }
    int b = blockIdx.x - 2500;
    const float *Wl, *Wr; ushort_t *Bh, *Bl; int FO, t;
    if (b < 16)      { Wl = Wl0; Wr = Wr0; Bh = Bh0; Bl = Bl0; FO = 128; t = b * 256 + threadIdx.x; }
    else if (b < 32) { Wl = Wl1; Wr = Wr1; Bh = Bh1; Bl = Bl1; FO = 128; t = (b - 16) * 256 + threadIdx.x; }
    else if (b < 40) { Wl = Wl2; Wr = Wr2; Bh = Bh2; Bl = Bl2; FO = 64;  t = (b - 32) * 256 + threadIdx.x; }
    else             { Wl = Wl3; Wr = Wr3; Bh = Bh3; Bl = Bl3; FO = 64;  t = (b - 40) * 256 + threadIdx.x; }
    int lane = t & 63, ks = (t >> 6) & 3, nt = t >> 8;
    int col = nt * 16 + (lane & 15);
    int k0 = ks * 32 + (lane >> 4) * 8;
    const float* W = (col < FO) ? Wl : Wr;
    int cc = (col < FO) ? col : col - FO;
#pragma unroll
    for (int j = 0; j < 8; ++j) {
        float v = W[(size_t)(k0 + j) * FO + cc];
        ushort_t h = f2bf(v);
        Bh[(size_t)t * 8 + j] = h;
        Bl[(size_t)t * 8 + j] = f2bf(v - bf2f(h));
    }
}

// ---------------------------------------------------------------------------
// Ordered exclusive scan (unchanged).
// ---------------------------------------------------------------------------
__global__ __launch_bounds__(256) void scan1_kernel(
    const int* __restrict__ cnt_i, const int* __restrict__ cnt_u,
    int* __restrict__ head_i, int* __restrict__ head_u,
    int* __restrict__ bsum_i, int* __restrict__ bsum_u)
{
    __shared__ int sh[256];
    int b = blockIdx.x, t = threadIdx.x;
    const int* cnt; int* head; int* bsum; int n, cb;
    if (b < GI) { cnt = cnt_i; head = head_i; bsum = bsum_i; n = NITEM; cb = b; }
    else        { cnt = cnt_u; head = head_u; bsum = bsum_u; n = NUSER; cb = b - GI; }
    int base = cb * 1024 + t * 4;
    int4 v = {0, 0, 0, 0};
    if (base + 3 < n) v = *(const int4*)(cnt + base);
    else {
        if (base + 0 < n) v.x = cnt[base + 0];
        if (base + 1 < n) v.y = cnt[base + 1];
        if (base + 2 < n) v.z = cnt[base + 2];
    }
    int s = v.x + v.y + v.z + v.w;
    sh[t] = s;
    __syncthreads();
    for (int o = 1; o < 256; o <<= 1) {
        int a = (t >= o) ? sh[t - o] : 0;
        __syncthreads();
        sh[t] += a;
        __syncthreads();
    }
    int excl = sh[t] - s;
    if (t == 255) bsum[cb] = sh[255];
    if (base + 0 < n) head[base + 0] = excl;
    if (base + 1 < n) head[base + 1] = excl + v.x;
    if (base + 2 < n) head[base + 2] = excl + v.x + v.y;
    if (base + 3 < n) head[base + 3] = excl + v.x + v.y + v.z;
}

__global__ __launch_bounds__(256) void scan23_kernel(
    int* __restrict__ head_i, int* __restrict__ head_u,
    const int* __restrict__ bsum_i, const int* __restrict__ bsum_u)
{
    __shared__ int sh[256];
    int b = blockIdx.x, t = threadIdx.x;
    int* head; const int* bsum; int n, cb;
    if (b < GI) { head = head_i; bsum = bsum_i; n = NITEM; cb = b; }
    else        { head = head_u; bsum = bsum_u; n = NUSER; cb = b - GI; }
    sh[t] = (t < cb) ? bsum[t] : 0;
    __syncthreads();
    for (int o = 128; o >= 1; o >>= 1) {
        if (t < o) sh[t] += sh[t + o];
        __syncthreads();
    }
    int add = sh[0];
    int base = cb * 1024 + t * 4;
#pragma unroll
    for (int k = 0; k < 4; ++k)
        if (base + k < n) head[base + k] += add;
}

// ---------------------------------------------------------------------------
// GEMM body: 512 thr / 8 waves; 128 rows/block as 4 sub-tiles of 32; B
// fragments register-resident (loaded ONCE/block); next sub-tile's A global
// loads prefetched into regs before MFMA phase (latency hides under compute).
// Wave owns NO/8 cols (CT = NO/128 16-col tiles). cols[0,FO)->ymsg, rest->z.
// LDS 16B-chunk XOR swizzle (chunk ^ (row&7)) -> conflict-free-enough (2-way).
// ---------------------------------------------------------------------------
template <int NO, bool ASPLIT>
__device__ __forceinline__ void gemm_body(
    const void* __restrict__ A_,
    const ushort_t* __restrict__ Bh, const ushort_t* __restrict__ Bl,
    ushort_t* __restrict__ ymsg, ushort_t* __restrict__ zout,
    int n, int row0, u32x4 (*ashH)[16], u32x4 (*ashL)[16])
{
    constexpr int CT = NO / 128;
    constexpr int FO = NO / 2;
    const int tid = threadIdx.x;
    const int lane = tid & 63, wv = tid >> 6;
    const int lr = lane & 15, lg = lane >> 4;
    const int row = tid >> 4, ch = tid & 15;   // staging coords: 512 = 32 x 16

    // B fragments once per block
    bf16x8 bfh[4][CT], bfl[4][CT];
#pragma unroll
    for (int ks = 0; ks < 4; ++ks)
#pragma unroll
        for (int ct = 0; ct < CT; ++ct) {
            size_t boff = ((size_t)((wv * CT + ct) * 4 + ks) * 64 + lane) * 8;
            bfh[ks][ct] = __builtin_bit_cast(bf16x8, *(const u32x4*)(Bh + boff));
            bfl[ks][ct] = __builtin_bit_cast(bf16x8, *(const u32x4*)(Bl + boff));
        }

    // preload sub-tile 0
    f32x4 c0 = {0.f, 0.f, 0.f, 0.f}, c1 = {0.f, 0.f, 0.f, 0.f};
    u32x4 cq = {0u, 0u, 0u, 0u};
    {
        int grow = row0 + row;
        if (grow < n) {
            if (ASPLIT) {
                const f32x4* p = (const f32x4*)((const float*)A_ + (size_t)grow * 128 + ch * 8);
                c0 = p[0]; c1 = p[1];
            } else {
                cq = *(const u32x4*)((const ushort_t*)A_ + (size_t)grow * 128 + ch * 8);
            }
        }
    }

#pragma unroll
    for (int st = 0; st < 4; ++st) {
        // ---- split + LDS write of current sub-tile ----
        int sc = ch ^ (row & 7);
        if (ASPLIT) {
            float e[8];
#pragma unroll
            for (int j = 0; j < 4; ++j) { e[j] = c0[j]; e[4 + j] = c1[j]; }
            uint hv[4], lv[4];
#pragma unroll
            for (int j = 0; j < 4; ++j) {
                ushort_t h0 = f2bf(e[2 * j]), h1 = f2bf(e[2 * j + 1]);
                hv[j] = (uint)h0 | ((uint)h1 << 16);
                ushort_t l0 = f2bf(e[2 * j] - bf2f(h0)), l1 = f2bf(e[2 * j + 1] - bf2f(h1));
                lv[j] = (uint)l0 | ((uint)l1 << 16);
            }
            u32x4 hq = {hv[0], hv[1], hv[2], hv[3]};
            u32x4 lq = {lv[0], lv[1], lv[2], lv[3]};
            ashH[row][sc] = hq;
            ashL[row][sc] = lq;
        } else {
            ashH[row][sc] = cq;
        }
        __syncthreads();

        // ---- prefetch next sub-tile (completes under the MFMAs below) ----
        if (st < 3) {
            c0 = f32x4{0.f, 0.f, 0.f, 0.f}; c1 = f32x4{0.f, 0.f, 0.f, 0.f};
            cq = u32x4{0u, 0u, 0u, 0u};
            int grow = row0 + (st + 1) * 32 + row;
            if (grow < n) {
                if (ASPLIT) {
                    const f32x4* p = (const f32x4*)((const float*)A_ + (size_t)grow * 128 + ch * 8);
                    c0 = p[0]; c1 = p[1];
                } else {
                    cq = *(const u32x4*)((const ushort_t*)A_ + (size_t)grow * 128 + ch * 8);
                }
            }
        }

        // ---- MFMA from LDS against register-resident B ----
        f32x4 acc[2][CT];
#pragma unroll
        for (int rt = 0; rt < 2; ++rt)
#pragma unroll
            for (int ct = 0; ct < CT; ++ct) { f32x4 zz = {0.f, 0.f, 0.f, 0.f}; acc[rt][ct] = zz; }
#pragma unroll
        for (int ks = 0; ks < 4; ++ks) {
            bf16x8 ah[2], al[2];
#pragma unroll
            for (int rt = 0; rt < 2; ++rt) {
                int arow = rt * 16 + lr;
                int pos = (ks * 4 + lg) ^ (arow & 7);
                ah[rt] = __builtin_bit_cast(bf16x8, ashH[arow][pos]);
                if (ASPLIT) al[rt] = __builtin_bit_cast(bf16x8, ashL[arow][pos]);
            }
#pragma unroll
            for (int ct = 0; ct < CT; ++ct)
#pragma unroll
                for (int rt = 0; rt < 2; ++rt) {
                    acc[rt][ct] = __builtin_amdgcn_mfma_f32_16x16x32_bf16(ah[rt], bfh[ks][ct], acc[rt][ct], 0, 0, 0);
                    acc[rt][ct] = __builtin_amdgcn_mfma_f32_16x16x32_bf16(ah[rt], bfl[ks][ct], acc[rt][ct], 0, 0, 0);
                    if (ASPLIT)
                        acc[rt][ct] = __builtin_amdgcn_mfma_f32_16x16x32_bf16(al[rt], bfh[ks][ct], acc[rt][ct], 0, 0, 0);
                }
        }

        // ---- C write (m89-verified layout: col = lane&15, row = (lane>>4)*4+reg) ----
#pragma unroll
        for (int rt = 0; rt < 2; ++rt)
#pragma unroll
            for (int ct = 0; ct < CT; ++ct) {
                int col = wv * (NO / 8) + ct * 16 + lr;
                bool ism = col < FO;
                ushort_t* dstp = ism ? ymsg : zout;
                int cc = ism ? col : col - FO;
#pragma unroll
                for (int r = 0; r < 4; ++r) {
                    int orow = row0 + st * 32 + rt * 16 + lg * 4 + r;
                    if (orow < n) dstp[(size_t)orow * FO + cc] = f2bf(acc[rt][ct][r]);
                }
            }
        __syncthreads();   // LDS reused next sub-tile
    }
}

// ---------------------------------------------------------------------------
// Fused [layer-1 GEMM (f32 A, hi/lo split, 3 products) | binned CSR fill].
// ---------------------------------------------------------------------------
__global__ __launch_bounds__(512) void gemmfill_kernel(
    const float* __restrict__ xu, const float* __restrict__ xi,
    const ushort_t* __restrict__ Bh0, const ushort_t* __restrict__ Bl0,
    const ushort_t* __restrict__ Bh1, const ushort_t* __restrict__ Bl1,
    ushort_t* __restrict__ y0, ushort_t* __restrict__ z0,
    ushort_t* __restrict__ y1, ushort_t* __restrict__ z1,
    const int* __restrict__ src, const int* __restrict__ dst,
    int* __restrict__ head_i, int* __restrict__ head_u,
    int* __restrict__ nbr_i, int* __restrict__ nbr_u)
{
    if (blockIdx.x >= NBG1) {
        int b = blockIdx.x - NBG1;
        int pass = b / (2 * FNCH);
        int rem  = b % (2 * FNCH);
        int dir  = rem / FNCH;
        int base = (rem % FNCH) * FCHUNK;
        int e_end = min(base + FCHUNK, NEDGE);
        if (dir == 0) {
            int lo = pass * (NITEM / 8), hi = lo + NITEM / 8;
            for (int e = base + threadIdx.x; e < e_end; e += 512) {
                int d = dst[e];
                if (d >= lo && d < hi) nbr_i[atomicAdd(&head_i[d], 1)] = src[e];
            }
        } else {
            int lo = pass * (NUSER / 8), hi = lo + NUSER / 8;
            for (int e = base + threadIdx.x; e < e_end; e += 512) {
                int s = src[e];
                if (s >= lo && s < hi) nbr_u[atomicAdd(&head_u[s], 1)] = dst[e];
            }
        }
        return;
    }
    __shared__ u32x4 ashH[32][16];
    __shared__ u32x4 ashL[32][16];
    if ((int)blockIdx.x < NBU1)
        gemm_body<256, true>(xu, Bh0, Bl0, y0, z0, NUSER, blockIdx.x * 128, ashH, ashL);
    else
        gemm_body<256, true>(xi, Bh1, Bl1, y1, z1, NITEM, (blockIdx.x - NBU1) * 128, ashH, ashL);
}

// ---------------------------------------------------------------------------
// Layer-2 GEMM (bf16 A, 2 products), both node types in one dispatch.
// ---------------------------------------------------------------------------
__global__ __launch_bounds__(512) void gemm2_kernel(
    const ushort_t* __restrict__ A0, const ushort_t* __restrict__ A1,
    const ushort_t* __restrict__ Bh0, const ushort_t* __restrict__ Bl0,
    const ushort_t* __restrict__ Bh1, const ushort_t* __restrict__ Bl1,
    ushort_t* __restrict__ y0, ushort_t* __restrict__ z0,
    ushort_t* __restrict__ y1, ushort_t* __restrict__ z1)
{
    __shared__ u32x4 ashH[32][16];
    if ((int)blockIdx.x < NBU1)
        gemm_body<128, false>(A0, Bh0, Bl0, y0, z0, NUSER, blockIdx.x * 128, ashH, ashH);
    else
        gemm_body<128, false>(A1, Bh1, Bl1, y1, z1, NITEM, (blockIdx.x - NBU1) * 128, ashH, ashH);
}

// ---------------------------------------------------------------------------
// Layer-1 gather + epilogue (unchanged).
// ---------------------------------------------------------------------------
__global__ __launch_bounds__(256) void gather1_kernel(
    const ushort_t* __restrict__ ymsg_u, const ushort_t* __restrict__ ymsg_i,
    const int* __restrict__ nbr_i, const int* __restrict__ head_i, const int* __restrict__ cnt_i,
    const int* __restrict__ nbr_u, const int* __restrict__ head_u, const int* __restrict__ cnt_u,
    const ushort_t* __restrict__ z_i, const ushort_t* __restrict__ z_u,
    const float* __restrict__ b_ui, const float* __restrict__ b_iu,
    ushort_t* __restrict__ h1_i, ushort_t* __restrict__ h1_u)
{
    int w = (blockIdx.x << 2) + (threadIdx.x >> 6);
    const ushort_t *ym, *z; const int *nbr, *head, *cnt; const float* bias;
    ushort_t* hout; int node;
    if (w < NITEM) { ym = ymsg_u; nbr = nbr_i; head = head_i; cnt = cnt_i; z = z_i; bias = b_ui; hout = h1_i; node = w; }
    else if (w < NITEM + NUSER) { ym = ymsg_i; nbr = nbr_u; head = head_u; cnt = cnt_u; z = z_u; bias = b_iu; hout = h1_u; node = w - NITEM; }
    else return;
    int lane = threadIdx.x & 63;
    int c = cnt[node], end = head[node];
    int j = end - c;
    const uint* Y = (const uint*)ym;
    float ax = 0.f, ay = 0.f;
    for (; j + 7 < end; j += 8) {
        uint u0 = Y[(size_t)nbr[j + 0] * 64 + lane];
        uint u1 = Y[(size_t)nbr[j + 1] * 64 + lane];
        uint u2 = Y[(size_t)nbr[j + 2] * 64 + lane];
        uint u3 = Y[(size_t)nbr[j + 3] * 64 + lane];
        uint u4 = Y[(size_t)nbr[j + 4] * 64 + lane];
        uint u5 = Y[(size_t)nbr[j + 5] * 64 + lane];
        uint u6 = Y[(size_t)nbr[j + 6] * 64 + lane];
        uint u7 = Y[(size_t)nbr[j + 7] * 64 + lane];
        ax += lo16f(u0) + lo16f(u1) + lo16f(u2) + lo16f(u3)
            + lo16f(u4) + lo16f(u5) + lo16f(u6) + lo16f(u7);
        ay += hi16f(u0) + hi16f(u1) + hi16f(u2) + hi16f(u3)
            + hi16f(u4) + hi16f(u5) + hi16f(u6) + hi16f(u7);
    }
    for (; j + 1 < end; j += 2) {
        uint u0 = Y[(size_t)nbr[j + 0] * 64 + lane];
        uint u1 = Y[(size_t)nbr[j + 1] * 64 + lane];
        ax += lo16f(u0) + lo16f(u1);
        ay += hi16f(u0) + hi16f(u1);
    }
    if (j < end) {
        uint u0 = Y[(size_t)nbr[j] * 64 + lane];
        ax += lo16f(u0); ay += hi16f(u0);
    }
    float m = 1.f / fmaxf((float)c, 1.f);
    uint zu = ((const uint*)z)[(size_t)node * 64 + lane];
    float vx = fmaxf(ax * m + lo16f(zu) + bias[lane * 2], 0.f);
    float vy = fmaxf(ay * m + hi16f(zu) + bias[lane * 2 + 1], 0.f);
    ((uint*)hout)[(size_t)node * 64 + lane] = (uint)f2bf(vx) | ((uint)f2bf(vy) << 16);
}

// ---------------------------------------------------------------------------
// Layer-2 gather + epilogue (unchanged).
// ---------------------------------------------------------------------------
__global__ __launch_bounds__(256) void gather2_kernel(
    const ushort_t* __restrict__ ymsg_u, const ushort_t* __restrict__ ymsg_i,
    const int* __restrict__ nbr_i, const int* __restrict__ head_i, const int* __restrict__ cnt_i,
    const int* __restrict__ nbr_u, const int* __restrict__ head_u, const int* __restrict__ cnt_u,
    const ushort_t* __restrict__ z_i, const ushort_t* __restrict__ z_u,
    const float* __restrict__ b_ui, const float* __restrict__ b_iu,
    ushort_t* __restrict__ h2_i, ushort_t* __restrict__ h2_u)
{
    int w = (blockIdx.x << 2) + (threadIdx.x >> 6);
    const ushort_t *ym, *z; const int *nbr, *head, *cnt; const float* bias;
    ushort_t* hout; int node;
    if (w < NITEM) { ym = ymsg_u; nbr = nbr_i; head = head_i; cnt = cnt_i; z = z_i; bias = b_ui; hout = h2_i; node = w; }
    else if (w < NITEM + NUSER) { ym = ymsg_i; nbr = nbr_u; head = head_u; cnt = cnt_u; z = z_u; bias = b_iu; hout = h2_u; node = w - NITEM; }
    else return;
    int lane = threadIdx.x & 63;
    int c = cnt[node], end = head[node];
    int j = end - c;
    float a = 0.f;
    for (; j + 7 < end; j += 8) {
        a += bf2f(ym[(size_t)nbr[j + 0] * 64 + lane]) + bf2f(ym[(size_t)nbr[j + 1] * 64 + lane])
           + bf2f(ym[(size_t)nbr[j + 2] * 64 + lane]) + bf2f(ym[(size_t)nbr[j + 3] * 64 + lane])
           + bf2f(ym[(size_t)nbr[j + 4] * 64 + lane]) + bf2f(ym[(size_t)nbr[j + 5] * 64 + lane])
           + bf2f(ym[(size_t)nbr[j + 6] * 64 + lane]) + bf2f(ym[(size_t)nbr[j + 7] * 64 + lane]);
    }
    for (; j + 1 < end; j += 2)
        a += bf2f(ym[(size_t)nbr[j] * 64 + lane]) + bf2f(ym[(size_t)nbr[j + 1] * 64 + lane]);
    if (j < end) a += bf2f(ym[(size_t)nbr[j] * 64 + lane]);
    float m = 1.f / fmaxf((float)c, 1.f);
    float v = a * m + bf2f(z[(size_t)node * 64 + lane]) + bias[lane];
    hout[(size_t)node * 64 + lane] = f2bf(v);
}

// ---------------------------------------------------------------------------
// Link head (unchanged).
// ---------------------------------------------------------------------------
__global__ __launch_bounds__(256) void predict_kernel(
    const int* __restrict__ el_src, const int* __restrict__ el_dst,
    const ushort_t* __restrict__ hu, const ushort_t* __restrict__ hi,
    float* __restrict__ out)
{
    int l = (blockIdx.x << 2) + (threadIdx.x >> 6);
    if (l >= NLINK) return;
    int lane = threadIdx.x & 63;
    int u = el_src[l];
    int it = el_dst[l];
    float v = bf2f(hu[(size_t)u * 64 + lane]) * bf2f(hi[(size_t)it * 64 + lane]);
#pragma unroll
    for (int o = 32; o >= 1; o >>= 1) v += __shfl_down(v, o, 64);
    if (lane == 0) out[l] = v;
}

extern "C" void kernel_launch(void* const* d_in, const int* in_sizes, int n_in,
                              void* d_out, int out_size, void* d_ws, size_t ws_size,
                              hipStream_t stream) {
    const float* x_user = (const float*)d_in[0];
    const float* x_item = (const float*)d_in[1];
    const int*   src_u  = (const int*)d_in[2];
    const int*   dst_i  = (const int*)d_in[3];
    const int*   el_src = (const int*)d_in[4];
    const int*   el_dst = (const int*)d_in[5];
    const float* Wl_ui1 = (const float*)d_in[6];
    const float* b_ui1  = (const float*)d_in[7];
    const float* Wr_ui1 = (const float*)d_in[8];
    const float* Wl_iu1 = (const float*)d_in[9];
    const float* b_iu1  = (const float*)d_in[10];
    const float* Wr_iu1 = (const float*)d_in[11];
    const float* Wl_ui2 = (const float*)d_in[12];
    const float* b_ui2  = (const float*)d_in[13];
    const float* Wr_ui2 = (const float*)d_in[14];
    const float* Wl_iu2 = (const float*)d_in[15];
    const float* b_iu2  = (const float*)d_in[16];
    const float* Wr_iu2 = (const float*)d_in[17];
    float* out = (float*)d_out;

    // ---- workspace layout (same as round 6) ----
    int* iw     = (int*)d_ws;
    int* cnt_i  = iw;              // [0, 50000)
    int* cnt_u  = iw + 50000;      // [50000, 150000)
    int* bsum_i = iw + 150000;     // 64 slots
    int* bsum_u = iw + 150064;     // 128 slots
    int* head_i = iw + 150192;
    int* head_u = iw + 200192;
    int* nbr_i  = iw + 300192;
    int* nbr_u  = iw + 940192;
    char* W8 = (char*)d_ws;
    size_t off = 6320768;
    ushort_t* Bh1u = (ushort_t*)(W8 + off); off += 65536;
    ushort_t* Bl1u = (ushort_t*)(W8 + off); off += 65536;
    ushort_t* Bh1i = (ushort_t*)(W8 + off); off += 65536;
    ushort_t* Bl1i = (ushort_t*)(W8 + off); off += 65536;
    ushort_t* Bh2u = (ushort_t*)(W8 + off); off += 32768;
    ushort_t* Bl2u = (ushort_t*)(W8 + off); off += 32768;
    ushort_t* Bh2i = (ushort_t*)(W8 + off); off += 32768;
    ushort_t* Bl2i = (ushort_t*)(W8 + off); off += 32768;   // off = 6,713,984
    ushort_t* h1_u = (ushort_t*)(W8 + off); off += (size_t)NUSER * 128 * 2;
    ushort_t* h1_i = (ushort_t*)(W8 + off); off += (size_t)NITEM * 128 * 2;
    size_t YB = off;                                        // 45,113,984
    ushort_t* ymsg_u = (ushort_t*)(W8 + YB);
    ushort_t* ymsg_i = (ushort_t*)(W8 + YB + 25600000);
    ushort_t* z_u    = (ushort_t*)(W8 + YB + 38400000);
    ushort_t* z_i    = (ushort_t*)(W8 + YB + 64000000);
    ushort_t* ymsg2_u = (ushort_t*)(W8 + YB);
    ushort_t* ymsg2_i = (ushort_t*)(W8 + YB + 12800000);
    ushort_t* z2_u    = (ushort_t*)(W8 + YB + 19200000);
    ushort_t* z2_i    = (ushort_t*)(W8 + YB + 32000000);
    ushort_t* h2_u    = (ushort_t*)(W8 + YB + 38400000);
    ushort_t* h2_i    = (ushort_t*)(W8 + YB + 51200000);

    // Zero ONLY cnt (atomic-incremented). Every other ws buffer is fully
    // written before read each call (head by scan, nbr by fill since
    // sum(cnt)=E, B by wprep, ymsg/z/h by gemm/gather).
    hipMemsetAsync(d_ws, 0, 150000 * sizeof(int), stream);

    // ---- [degree count | weight pack] ----
    countw_kernel<<<2548, 256, 0, stream>>>(
        src_u, dst_i, cnt_u, cnt_i,
        Wl_ui1, Wr_iu1, Wl_iu1, Wr_ui1, Wl_ui2, Wr_iu2, Wl_iu2, Wr_ui2,
        Bh1u, Bl1u, Bh1i, Bl1i, Bh2u, Bl2u, Bh2i, Bl2i);

    // ---- ordered exclusive scan ----
    scan1_kernel<<<GI + GU, 256, 0, stream>>>(cnt_i, cnt_u, head_i, head_u, bsum_i, bsum_u);
    scan23_kernel<<<GI + GU, 256, 0, stream>>>(head_i, head_u, bsum_i, bsum_u);

    // ---- [layer-1 GEMM (transform-first) | binned CSR fill] ----
    gemmfill_kernel<<<NBG1 + 8 * 2 * FNCH, 512, 0, stream>>>(
        x_user, x_item, Bh1u, Bl1u, Bh1i, Bl1i,
        ymsg_u, z_u, ymsg_i, z_i,
        src_u, dst_i, head_i, head_u, nbr_i, nbr_u);

    // ---- layer 1 gather ----
    gather1_kernel<<<(NITEM + NUSER) / 4, 256, 0, stream>>>(
        ymsg_u, ymsg_i, nbr_i, head_i, cnt_i, nbr_u, head_u, cnt_u,
        z_i, z_u, b_ui1, b_iu1, h1_i, h1_u);

    // ---- layer 2 ----
    gemm2_kernel<<<NBG1, 512, 0, stream>>>(
        h1_u, h1_i, Bh2u, Bl2u, Bh2i, Bl2i,
        ymsg2_u, z2_u, ymsg2_i, z2_i);
    gather2_kernel<<<(NITEM + NUSER) / 4, 256, 0, stream>>>(
        ymsg2_u, ymsg2_i, nbr_i, head_i, cnt_i, nbr_u, head_u, cnt_u,
        z2_i, z2_u, b_ui2, b_iu2, h2_i, h2_u);

    // ---- link prediction head ----
    predict_kernel<<<NLINK / 4, 256, 0, stream>>>(el_src, el_dst, h2_u, h2_i, out);
}